// Round 6
// baseline (332.412 us; speedup 1.0000x reference)
//
#include <hip/hip_runtime.h>
#include <hip/hip_bf16.h>
#include <math.h>

#define NN 50000     // nodes
#define NE 400000    // edges
#define HH 4         // heads
#define CC 64        // per-head dim
#define HC 256       // H*C
#define GG 64        // graphs
#define NB 196       // scan blocks: ceil(NN/256)
#define WCB 640      // wconv blocks

typedef short v8s __attribute__((ext_vector_type(8)));
typedef float f32x4 __attribute__((ext_vector_type(4)));

static __device__ inline unsigned short f2bf(float v) {
  __hip_bfloat16 b = __float2bfloat16(v);
  return *reinterpret_cast<unsigned short*>(&b);
}
// packed bf16 pair -> f32 (bf16 value = bit pattern << 16)
static __device__ inline float bflo(unsigned u) { return __uint_as_float(u << 16); }
static __device__ inline float bfhi(unsigned u) { return __uint_as_float(u & 0xffff0000u); }

// width-16 xor-butterfly step via ds_swizzle BitMode: ONE DS instr, no VALU
// addr math. offset = (xor<<10)|0x1F.
static __device__ inline float swz_xor(float v, int imm) {
  switch (imm) {
    case 8: return __int_as_float(__builtin_amdgcn_ds_swizzle(__float_as_int(v), 0x201F));
    case 4: return __int_as_float(__builtin_amdgcn_ds_swizzle(__float_as_int(v), 0x101F));
    case 2: return __int_as_float(__builtin_amdgcn_ds_swizzle(__float_as_int(v), 0x081F));
    default: return __int_as_float(__builtin_amdgcn_ds_swizzle(__float_as_int(v), 0x041F));
  }
}

// async global->LDS, 16B per lane. LDS dest is wave-uniform base + lane*16.
static __device__ inline void gload_lds16(const void* g, void* l) {
  __builtin_amdgcn_global_load_lds(
      (const __attribute__((address_space(1))) void*)g,
      (__attribute__((address_space(3))) void*)l, 16, 0, 0);
}

// ---- head kernel: W preps + setup (zero deg/pool, seg bounds) ----
// bid < WCB        : wconv  W[K,256] f32 -> Wt bf16 [256][K]
// bid < WCB+NB     : setup
__global__ __launch_bounds__(256) void head_kernel(
    const float* __restrict__ g1_wl, const float* __restrict__ g1_wr,
    const float* __restrict__ g2_wl, const float* __restrict__ g2_wr,
    unsigned short* __restrict__ wt1, unsigned short* __restrict__ wt2,
    const int* __restrict__ batch, int* __restrict__ deg,
    float* __restrict__ pool, int* __restrict__ bounds) {
  int bid = blockIdx.x, tid = threadIdx.x;
  if (bid < WCB) {
    int idx = bid * 256 + tid;
    const float* W; unsigned short* Wt; int K; int base;
    if (idx < 16384)        { W = g1_wl; Wt = wt1;                     K = 64;  base = idx; }
    else if (idx < 32768)   { W = g1_wr; Wt = wt1 + (size_t)256 * 64;  K = 64;  base = idx - 16384; }
    else if (idx < 98304)   { W = g2_wl; Wt = wt2;                     K = 256; base = idx - 32768; }
    else if (idx < 163840)  { W = g2_wr; Wt = wt2 + (size_t)256 * 256; K = 256; base = idx - 98304; }
    else return;
    int k = base >> 8, n = base & 255;
    Wt[n * K + k] = f2bf(W[base]);
  } else {
    int sb = bid - WCB;                  // 0..NB-1
    int i = sb * 256 + tid;
    if (i < NN) deg[i] = 0;
    if (sb < GG) pool[sb * 256 + tid] = 0.f;
    if (sb == NB - 1 && tid <= GG) {
      int g = tid, lo = 0, hi = NN;
      while (lo < hi) {
        int mid = (lo + hi) >> 1;
        if (batch[mid] < g) lo = mid + 1; else hi = mid;
      }
      bounds[g] = lo;
    }
  }
}

// ------- layer-1 matmul WITH fused encoder -------
// A-tile (128x64 bf16) = relu(x[rows,0:8] @ enc_w + enc_b), computed in-block
// (131 KFLOP) instead of staging h0 from HBM. B double-buffered via
// global_load_lds w16 (pre-swizzled source chunk). Numerics identical to the
// old encoder kernel (same FMA order, same bf16 rounding point).
__global__ __launch_bounds__(256) void matmul_enc_kernel(
    const float* __restrict__ x, const float* __restrict__ enc_w,
    const float* __restrict__ enc_b,
    const unsigned short* __restrict__ Wt, const float* __restrict__ bias,
    unsigned short* __restrict__ outL, unsigned short* __restrict__ outR, int M) {
  constexpr int K = 64;
  const int mmb = ((M + 127) >> 7) << 2;
  int bid = blockIdx.x;
  {
    int q = mmb >> 3, r = mmb & 7;
    int xcd = bid & 7, off2 = bid >> 3;
    bid = (xcd < r ? xcd * (q + 1) : r * (q + 1) + (xcd - r) * q) + off2;
  }
  // smem map (shorts): a_enc [0,8192) ; b0 [8192,12288) ; b1 [12288,16384)
  // wT/eb overlap b1 (used only during encoder phase, before b1 is staged)
  __shared__ __attribute__((aligned(16))) unsigned short smem[16384];
  unsigned short* a_enc = smem;
  unsigned short* b0 = smem + 8192;
  unsigned short* b1 = smem + 12288;
  float* wT = (float*)(smem + 12288);      // [64][8] transposed enc_w (2KB)
  float* eb = wT + 512;                    // [64]

  const int tid = threadIdx.x;
  const int wave = tid >> 6;
  const int lane = tid & 63;
  const int quad = lane >> 4;
  const int lrow = lane & 15;
  const int wr = (wave & 1) * 64;
  const int wc = (wave >> 1) * 64;
  const int r0 = (bid >> 2) * 128;
  const int n0 = (bid & 3) * 128;

  // ---- encoder phase: compute A-tile into a_enc (XOR-swizzled chunks) ----
  for (int idx = tid; idx < 512; idx += 256)
    wT[(idx & 63) * 8 + (idx >> 6)] = enc_w[idx];
  if (tid < 64) eb[tid] = enc_b[tid];
  const int erow = tid >> 1;               // 0..127
  const int ehalf = tid & 1;
  int gnode = r0 + erow; if (gnode >= M) gnode = M - 1;
  const float4* xr4 = (const float4*)(x + (size_t)gnode * 8);
  float4 xa = xr4[0], xb = xr4[1];
  __syncthreads();
  unsigned short abuf[32];
#pragma unroll
  for (int j = 0; j < 32; ++j) {
    int col = ehalf * 32 + j;
    const float4* w4 = (const float4*)&wT[col * 8];
    float4 w0 = w4[0], w1 = w4[1];
    float acc = eb[col];
    acc += xa.x * w0.x; acc += xa.y * w0.y; acc += xa.z * w0.z; acc += xa.w * w0.w;
    acc += xb.x * w1.x; acc += xb.y * w1.y; acc += xb.z * w1.z; acc += xb.w * w1.w;
    abuf[j] = f2bf(fmaxf(acc, 0.f));
  }
  __syncthreads();                         // wT/eb reads done -> b1 reusable
#pragma unroll
  for (int cc4 = 0; cc4 < 4; ++cc4) {
    int cc = ehalf * 4 + cc4;              // chunk 0..7 (8 shorts each)
    int scc = cc ^ (erow & 7);             // row-XOR: conflict-light reads
    *(uint4*)&a_enc[erow * 64 + scc * 8] = *(uint4*)&abuf[cc4 * 8];
  }

  // ---- B staging geometry (same as proven kernel) ----
  const int lrB0 = (wave * 2) * 16 + (lane >> 2);
  const int lrB1 = lrB0 + 16;
  const int c    = lane & 3;
  const int cs0  = c ^ ((lrB0 >> 1) & 3);
  const int cs1  = c ^ ((lrB1 >> 1) & 3);
  const unsigned short* srcB0 = Wt + (size_t)(n0 + lrB0) * K + cs0 * 8;
  const unsigned short* srcB1 = Wt + (size_t)(n0 + lrB1) * K + cs1 * 8;
  const int doff0 = (wave * 2 + 0) * 512;
  const int doff1 = (wave * 2 + 1) * 512;
  const int qsw = (quad ^ ((lrow >> 1) & 3)) * 8;

  f32x4 acc[4][4];
#pragma unroll
  for (int i = 0; i < 4; ++i)
#pragma unroll
    for (int j = 0; j < 4; ++j) acc[i][j] = (f32x4){0.f, 0.f, 0.f, 0.f};

  gload_lds16(srcB0, &b0[doff0]);
  gload_lds16(srcB1, &b0[doff1]);
  __syncthreads();                         // a_enc writes + B0 ready

#pragma unroll
  for (int t = 0; t < 2; ++t) {
    if (t == 0) {                          // stage B k0=32 -> b1 (async)
      gload_lds16(srcB0 + 32, &b1[doff0]);
      gload_lds16(srcB1 + 32, &b1[doff1]);
    }
    const unsigned short* bb = t ? b1 : b0;
    v8s af[4], bf[4];
#pragma unroll
    for (int rt = 0; rt < 4; ++rt) {
      int R = wr + rt * 16 + lrow;
      af[rt] = *(const v8s*)&a_enc[R * 64 + ((t * 4 + quad) ^ (R & 7)) * 8];
    }
#pragma unroll
    for (int ct = 0; ct < 4; ++ct)
      bf[ct] = *(const v8s*)&bb[(wc + ct * 16 + lrow) * 32 + qsw];
#pragma unroll
    for (int rt = 0; rt < 4; ++rt)
#pragma unroll
      for (int ct = 0; ct < 4; ++ct)
        acc[rt][ct] = __builtin_amdgcn_mfma_f32_16x16x32_bf16(af[rt], bf[ct], acc[rt][ct], 0, 0, 0);
    __syncthreads();
  }

  const bool isL = (n0 < 256);
  unsigned short* outp = isL ? outL : outR;
  const int cbase = isL ? n0 : (n0 - 256);
  constexpr int SP = 136;
  unsigned short* stage = smem;            // a_enc region free now

#pragma unroll
  for (int rt = 0; rt < 4; ++rt) {
    __syncthreads();
#pragma unroll
    for (int ct = 0; ct < 4; ++ct) {
      int col = wc + ct * 16 + lrow;
      float b = isL ? bias[cbase + col] : 0.f;
#pragma unroll
      for (int r = 0; r < 4; ++r) {
        int sr = (wave & 1) * 16 + quad * 4 + r;
        stage[sr * SP + col] = f2bf(acc[rt][ct][r] + b);
      }
    }
    __syncthreads();
    int sr = tid >> 3;
    int c0 = (tid & 7) * 16;
    int grow = r0 + (sr >> 4) * 64 + rt * 16 + (sr & 15);
    if (grow < M) {
      uint4 v0 = *(const uint4*)&stage[sr * SP + c0];
      uint4 v1 = *(const uint4*)&stage[sr * SP + c0 + 8];
      *(uint4*)&outp[(size_t)grow * 256 + cbase + c0] = v0;
      *(uint4*)&outp[(size_t)grow * 256 + cbase + c0 + 8] = v1;
    }
  }
}

// ------- generic MFMA matmul (layer 2, K=256): proven 2-phase pipeline -------
template <int K>
__global__ __launch_bounds__(256) void matmul_mfma_kernel(
    const unsigned short* __restrict__ A, const unsigned short* __restrict__ Wt,
    const float* __restrict__ bias,
    unsigned short* __restrict__ outL, unsigned short* __restrict__ outR, int M) {
  const int mmb = ((M + 127) >> 7) << 2;
  int bid = blockIdx.x;
  {
    int q = mmb >> 3, r = mmb & 7;
    int xcd = bid & 7, off2 = bid >> 3;
    bid = (xcd < r ? xcd * (q + 1) : r * (q + 1) + (xcd - r) * q) + off2;
  }
  __shared__ __attribute__((aligned(16))) unsigned short lds[16384];
  const int tid = threadIdx.x;
  const int wave = tid >> 6;
  const int lane = tid & 63;
  const int quad = lane >> 4;
  const int lrow = lane & 15;
  const int wr = (wave & 1) * 64;
  const int wc = (wave >> 1) * 64;
  const int r0 = (bid >> 2) * 128;
  const int n0 = (bid & 3) * 128;

  f32x4 acc[4][4];
#pragma unroll
  for (int i = 0; i < 4; ++i)
#pragma unroll
    for (int j = 0; j < 4; ++j) acc[i][j] = (f32x4){0.f, 0.f, 0.f, 0.f};

  const int lrA0 = (wave * 2) * 16 + (lane >> 2);
  const int lrA1 = lrA0 + 16;
  const int c    = lane & 3;
  const int cs0  = c ^ ((lrA0 >> 1) & 3);
  const int cs1  = c ^ ((lrA1 >> 1) & 3);
  int ga0 = r0 + lrA0; if (ga0 >= M) ga0 = M - 1;
  int ga1 = r0 + lrA1; if (ga1 >= M) ga1 = M - 1;
  const unsigned short* srcA0 = A  + (size_t)ga0 * K + cs0 * 8;
  const unsigned short* srcA1 = A  + (size_t)ga1 * K + cs1 * 8;
  const unsigned short* srcB0 = Wt + (size_t)(n0 + lrA0) * K + cs0 * 8;
  const unsigned short* srcB1 = Wt + (size_t)(n0 + lrA1) * K + cs1 * 8;
  const int doff0 = (wave * 2 + 0) * 512;
  const int doff1 = (wave * 2 + 1) * 512;
  const int qsw = (quad ^ ((lrow >> 1) & 3)) * 8;

  constexpr int NT = K / 32;
  gload_lds16(srcA0, &lds[doff0]);
  gload_lds16(srcA1, &lds[doff1]);
  gload_lds16(srcB0, &lds[4096 + doff0]);
  gload_lds16(srcB1, &lds[4096 + doff1]);
  __syncthreads();

  int cur = 0;
#pragma unroll
  for (int t = 0; t < NT; ++t) {
    if (t + 1 < NT) {
      const int k0 = (t + 1) * 32;
      const int nb = (cur ^ 1) * 8192;
      gload_lds16(srcA0 + k0, &lds[nb + doff0]);
      gload_lds16(srcA1 + k0, &lds[nb + doff1]);
      gload_lds16(srcB0 + k0, &lds[nb + 4096 + doff0]);
      gload_lds16(srcB1 + k0, &lds[nb + 4096 + doff1]);
    }
    const unsigned short* base = &lds[cur * 8192];
    v8s af[4], bf[4];
#pragma unroll
    for (int rt = 0; rt < 4; ++rt)
      af[rt] = *(const v8s*)&base[(wr + rt * 16 + lrow) * 32 + qsw];
#pragma unroll
    for (int ct = 0; ct < 4; ++ct)
      bf[ct] = *(const v8s*)&base[4096 + (wc + ct * 16 + lrow) * 32 + qsw];
#pragma unroll
    for (int rt = 0; rt < 4; ++rt)
#pragma unroll
      for (int ct = 0; ct < 4; ++ct)
        acc[rt][ct] = __builtin_amdgcn_mfma_f32_16x16x32_bf16(af[rt], bf[ct], acc[rt][ct], 0, 0, 0);
    __syncthreads();
    cur ^= 1;
  }

  const bool isL = (n0 < 256);
  unsigned short* outp = isL ? outL : outR;
  const int cbase = isL ? n0 : (n0 - 256);
  constexpr int SP = 136;
  unsigned short* stage = lds;

#pragma unroll
  for (int rt = 0; rt < 4; ++rt) {
    __syncthreads();
#pragma unroll
    for (int ct = 0; ct < 4; ++ct) {
      int col = wc + ct * 16 + lrow;
      float b = isL ? bias[cbase + col] : 0.f;
#pragma unroll
      for (int r = 0; r < 4; ++r) {
        int sr = (wave & 1) * 16 + quad * 4 + r;
        stage[sr * SP + col] = f2bf(acc[rt][ct][r] + b);
      }
    }
    __syncthreads();
    int sr = tid >> 3;
    int c0 = (tid & 7) * 16;
    int grow = r0 + (sr >> 4) * 64 + rt * 16 + (sr & 15);
    if (grow < M) {
      uint4 v0 = *(const uint4*)&stage[sr * SP + c0];
      uint4 v1 = *(const uint4*)&stage[sr * SP + c0 + 8];
      *(uint4*)&outp[(size_t)grow * 256 + cbase + c0] = v0;
      *(uint4*)&outp[(size_t)grow * 256 + cbase + c0 + 8] = v1;
    }
  }
}

// ---------------- CSR build (proven 3-kernel scan chain) ----------------
__global__ void degree_kernel(const int* __restrict__ ei, int* __restrict__ deg) {
  int e = blockIdx.x * 256 + threadIdx.x;
  if (e < NE) atomicAdd(&deg[ei[NE + e]], 1);
}

__global__ __launch_bounds__(256) void blocksum_kernel(
    const int* __restrict__ deg, int* __restrict__ bsum) {
  int t = threadIdx.x;
  int i = blockIdx.x * 256 + t;
  int v = (i < NN) ? deg[i] : 0;
#pragma unroll
  for (int off = 32; off; off >>= 1) v += __shfl_down(v, off, 64);
  __shared__ int ws[4];
  if ((t & 63) == 0) ws[t >> 6] = v;
  __syncthreads();
  if (t == 0) bsum[blockIdx.x] = ws[0] + ws[1] + ws[2] + ws[3];
}

__global__ __launch_bounds__(256) void blockscan_kernel(
    const int* __restrict__ bsum, int* __restrict__ bpre, int* __restrict__ rowstart) {
  __shared__ int s[256];
  int t = threadIdx.x;
  int v = (t < NB) ? bsum[t] : 0;
  s[t] = v;
  __syncthreads();
  for (int off = 1; off < 256; off <<= 1) {
    int x = s[t];
    int y = (t >= off) ? s[t - off] : 0;
    __syncthreads();
    s[t] = x + y;
    __syncthreads();
  }
  if (t < NB) bpre[t] = s[t] - v;
  if (t == 255) rowstart[NN] = s[255];
}

__global__ __launch_bounds__(256) void rowstart_kernel(
    const int* __restrict__ deg, const int* __restrict__ bpre,
    int* __restrict__ rowstart, int* __restrict__ cursor) {
  __shared__ int s[256];
  int t = threadIdx.x;
  int i = blockIdx.x * 256 + t;
  int v = (i < NN) ? deg[i] : 0;
  s[t] = v;
  __syncthreads();
  for (int off = 1; off < 256; off <<= 1) {
    int x = s[t];
    int y = (t >= off) ? s[t - off] : 0;
    __syncthreads();
    s[t] = x + y;
    __syncthreads();
  }
  if (i < NN) {
    int rs = bpre[blockIdx.x] + s[t] - v;
    rowstart[i] = rs;
    cursor[i] = rs;
  }
}

// CSR fill: int2 (src BYTE OFFSET = src*512, ea-bits) -> one aligned 8B store.
__global__ void fill_kernel(const int* __restrict__ ei, const float* __restrict__ ea,
                            int* __restrict__ cursor, int2* __restrict__ edges) {
  int e = blockIdx.x * 256 + threadIdx.x;
  if (e < NE) {
    int d = ei[NE + e];
    int pos = atomicAdd(&cursor[d], 1);
    edges[pos] = make_int2(ei[e] << 9, __float_as_int(ea[e]));
  }
}

// ---------------- fused GATv2 edge phase: wave per dst node (r4 body) ----
__global__ __launch_bounds__(256) void gat_fused_kernel(
    const int* __restrict__ rowstart, const int2* __restrict__ edges,
    const unsigned short* __restrict__ xl, const unsigned short* __restrict__ xr,
    const float* __restrict__ we, const float* __restrict__ att,
    const float* __restrict__ bias, unsigned short* __restrict__ outb) {
  int node = (blockIdx.x * 256 + threadIdx.x) >> 6;
  int lane = threadIdx.x & 63;
  int r0 = __builtin_amdgcn_readfirstlane(rowstart[node]);
  int r1 = __builtin_amdgcn_readfirstlane(rowstart[node + 1]);
  const char* xlb = (const char*)xl;          // UNIFORM gather base
  const unsigned lane8 = (unsigned)lane * 8u;
  uint2 rp = ((const uint2*)xr)[(size_t)node * 64 + lane];
  float4 r = make_float4(bflo(rp.x), bfhi(rp.x), bflo(rp.y), bfhi(rp.y));
  float4 wv = ((const float4*)we)[lane];
  float4 at = ((const float4*)att)[lane];
  const float LOG2E = 1.442695040888963f;
  at.x *= LOG2E; at.y *= LOG2E; at.z *= LOG2E; at.w *= LOG2E;
  float4 acc = make_float4(0.f, 0.f, 0.f, 0.f);
  float denom = 0.f;

  auto edge_step = [&](float eav, uint2 p) {
    float4 a = make_float4(bflo(p.x), bfhi(p.x), bflo(p.y), bfhi(p.y));
    float s0 = a.x + (r.x + eav * wv.x);
    float s1 = a.y + (r.y + eav * wv.y);
    float s2 = a.z + (r.z + eav * wv.z);
    float s3 = a.w + (r.w + eav * wv.w);
    s0 = fmaxf(s0, 0.2f * s0);
    s1 = fmaxf(s1, 0.2f * s1);
    s2 = fmaxf(s2, 0.2f * s2);
    s3 = fmaxf(s3, 0.2f * s3);
    float p4 = (s0 * at.x + s1 * at.y) + (s2 * at.z + s3 * at.w);
    p4 += swz_xor(p4, 8);
    p4 += swz_xor(p4, 4);
    p4 += swz_xor(p4, 2);
    p4 += swz_xor(p4, 1);
    float ex = exp2f(p4);
    denom += ex;
    acc.x += ex * a.x; acc.y += ex * a.y; acc.z += ex * a.z; acc.w += ex * a.w;
  };
  auto gath = [&](int byteoff) {
    return *(const uint2*)(xlb + (unsigned)byteoff + lane8);
  };

  int i = r0;
  if (i + 8 <= r1) {
    int2 e0 = edges[i];     int2 e1 = edges[i + 1];
    int2 e2 = edges[i + 2]; int2 e3 = edges[i + 3];
    uint2 p0 = gath(e0.x), p1 = gath(e1.x), p2 = gath(e2.x), p3 = gath(e3.x);
    for (; i + 8 <= r1; i += 4) {
      int2 f0 = edges[i + 4]; int2 f1 = edges[i + 5];
      int2 f2 = edges[i + 6]; int2 f3 = edges[i + 7];
      uint2 q0 = gath(f0.x), q1 = gath(f1.x), q2 = gath(f2.x), q3 = gath(f3.x);
      edge_step(__int_as_float(e0.y), p0);
      edge_step(__int_as_float(e1.y), p1);
      edge_step(__int_as_float(e2.y), p2);
      edge_step(__int_as_float(e3.y), p3);
      e0 = f0; e1 = f1; e2 = f2; e3 = f3;
      p0 = q0; p1 = q1; p2 = q2; p3 = q3;
    }
    edge_step(__int_as_float(e0.y), p0);
    edge_step(__int_as_float(e1.y), p1);
    edge_step(__int_as_float(e2.y), p2);
    edge_step(__int_as_float(e3.y), p3);
    i += 4;
  } else if (i + 4 <= r1) {
    int2 e0 = edges[i];     int2 e1 = edges[i + 1];
    int2 e2 = edges[i + 2]; int2 e3 = edges[i + 3];
    uint2 p0 = gath(e0.x), p1 = gath(e1.x), p2 = gath(e2.x), p3 = gath(e3.x);
    edge_step(__int_as_float(e0.y), p0);
    edge_step(__int_as_float(e1.y), p1);
    edge_step(__int_as_float(e2.y), p2);
    edge_step(__int_as_float(e3.y), p3);
    i += 4;
  }
  for (; i < r1; ++i) {
    int2 e = edges[i];
    edge_step(__int_as_float(e.y), gath(e.x));
  }

  float inv = 1.f / (denom + 1e-16f);
  float4 bv = ((const float4*)bias)[lane];
  float4 o;
  o.x = fmaxf(acc.x * inv + bv.x, 0.f);
  o.y = fmaxf(acc.y * inv + bv.y, 0.f);
  o.z = fmaxf(acc.z * inv + bv.z, 0.f);
  o.w = fmaxf(acc.w * inv + bv.w, 0.f);
  uint2 pk;
  pk.x = (unsigned)f2bf(o.x) | ((unsigned)f2bf(o.y) << 16);
  pk.y = (unsigned)f2bf(o.z) | ((unsigned)f2bf(o.w) << 16);
  ((uint2*)outb)[(size_t)node * 64 + lane] = pk;
}

// ---------------- pooling (bf16 input): block = 64 nodes, 4 rg x 64 lanes ----
__global__ __launch_bounds__(256) void pool_kernel(
    const unsigned short* __restrict__ h, const int* __restrict__ batch,
    float* __restrict__ pool) {
  int rg = threadIdx.x >> 6;
  int lane = threadIdx.x & 63;
  int n0 = blockIdx.x * 64;
  const uint2* h2 = (const uint2*)h;
  float4 acc = make_float4(0.f, 0.f, 0.f, 0.f);
  int cur = -1;
#pragma unroll 4
  for (int i = 0; i < 16; ++i) {
    int n = n0 + rg + 4 * i;
    if (n >= NN) break;
    int b = batch[n];
    if (b != cur) {
      if (cur >= 0) {
        float* p = &pool[cur * 256 + lane * 4];
        atomicAdd(p + 0, acc.x); atomicAdd(p + 1, acc.y);
        atomicAdd(p + 2, acc.z); atomicAdd(p + 3, acc.w);
      }
      cur = b;
      acc = make_float4(0.f, 0.f, 0.f, 0.f);
    }
    uint2 v = h2[(size_t)n * 64 + lane];
    acc.x += bflo(v.x); acc.y += bfhi(v.x);
    acc.z += bflo(v.y); acc.w += bfhi(v.y);
  }
  if (cur >= 0) {
    float* p = &pool[cur * 256 + lane * 4];
    atomicAdd(p + 0, acc.x); atomicAdd(p + 1, acc.y);
    atomicAdd(p + 2, acc.z); atomicAdd(p + 3, acc.w);
  }
}

// ---------------- final MLP: one block (128 thr) per graph ----------------
__global__ __launch_bounds__(128) void mlp_kernel(
    const float* __restrict__ pool, const int* __restrict__ bounds,
    const float* __restrict__ p1w, const float* __restrict__ p1b,
    const float* __restrict__ lng, const float* __restrict__ lnb,
    const float* __restrict__ p2w, const float* __restrict__ p2b,
    const float* __restrict__ hw, const float* __restrict__ hb,
    float* __restrict__ out) {
  __shared__ float sg[256];
  __shared__ float red[128];
  __shared__ float sz[128];
  __shared__ float s2[64];
  int b = blockIdx.x, tid = threadIdx.x;
  float cntf = (float)(bounds[b + 1] - bounds[b]);
  float invc = 1.f / fmaxf(cntf, 1.f);
  for (int i = tid; i < 256; i += 128) sg[i] = pool[b * 256 + i] * invc;
  __syncthreads();
  float z = p1b[tid];
  for (int k = 0; k < 256; ++k) z += sg[k] * p1w[k * 128 + tid];
  red[tid] = z; __syncthreads();
  for (int off = 64; off; off >>= 1) { if (tid < off) red[tid] += red[tid + off]; __syncthreads(); }
  float mu = red[0] * (1.f / 128.f);
  __syncthreads();
  float d = z - mu;
  red[tid] = d * d; __syncthreads();
  for (int off = 64; off; off >>= 1) { if (tid < off) red[tid] += red[tid + off]; __syncthreads(); }
  float var = red[0] * (1.f / 128.f);
  float zn = d * rsqrtf(var + 1e-5f) * lng[tid] + lnb[tid];
  sz[tid] = fmaxf(zn, 0.f);
  __syncthreads();
  if (tid < 64) {
    float a = p2b[tid];
    for (int k = 0; k < 128; ++k) a += sz[k] * p2w[k * 64 + tid];
    s2[tid] = fmaxf(a, 0.f);
  }
  __syncthreads();
  if (tid < 64) {
    float p = s2[tid] * hw[tid];
    for (int off = 32; off; off >>= 1) p += __shfl_down(p, off, 64);
    if (tid == 0) out[b] = p + hb[0];
  }
}

extern "C" void kernel_launch(void* const* d_in, const int* in_sizes, int n_in,
                              void* d_out, int out_size, void* d_ws, size_t ws_size,
                              hipStream_t stream) {
  const float* x      = (const float*)d_in[0];
  const int*   ei     = (const int*)d_in[1];
  const float* ea     = (const float*)d_in[2];
  const int*   batch  = (const int*)d_in[3];
  const float* enc_w  = (const float*)d_in[4];
  const float* enc_b  = (const float*)d_in[5];
  const float* g1_wl  = (const float*)d_in[6];
  const float* g1_bl  = (const float*)d_in[7];
  const float* g1_wr  = (const float*)d_in[8];
  const float* g1_we  = (const float*)d_in[9];
  const float* g1_att = (const float*)d_in[10];
  const float* g1_b   = (const float*)d_in[11];
  const float* g2_wl  = (const float*)d_in[12];
  const float* g2_bl  = (const float*)d_in[13];
  const float* g2_wr  = (const float*)d_in[14];
  const float* g2_we  = (const float*)d_in[15];
  const float* g2_att = (const float*)d_in[16];
  const float* g2_b   = (const float*)d_in[17];
  const float* p1_w   = (const float*)d_in[18];
  const float* p1_b   = (const float*)d_in[19];
  const float* ln_g   = (const float*)d_in[20];
  const float* ln_b   = (const float*)d_in[21];
  const float* p2_w   = (const float*)d_in[22];
  const float* p2_b   = (const float*)d_in[23];
  const float* head_w = (const float*)d_in[24];
  const float* head_b = (const float*)d_in[25];
  float* out = (float*)d_out;

  char* ws = (char*)d_ws;
  size_t off = 0;
  auto alloc = [&](size_t bytes) -> void* {
    void* p = ws + off;
    off = (off + bytes + 255) & ~(size_t)255;
    return p;
  };
  unsigned short* xl   = (unsigned short*)alloc((size_t)NN * HC * 2);
  unsigned short* xr   = (unsigned short*)alloc((size_t)NN * HC * 2);
  unsigned short* hb16 = (unsigned short*)alloc((size_t)NN * HC * 2);
  unsigned short* wt1  = (unsigned short*)alloc((size_t)512 * 64 * 2);
  unsigned short* wt2  = (unsigned short*)alloc((size_t)512 * 256 * 2);
  float* pool      = (float*)alloc((size_t)GG * HC * 4);
  int*   deg       = (int*)alloc((size_t)NN * 4);
  int*   rowstart  = (int*)alloc((size_t)(NN + 1) * 4);
  int*   cursor    = (int*)alloc((size_t)NN * 4);
  int*   bsum      = (int*)alloc((size_t)NB * 4);
  int*   bpre      = (int*)alloc((size_t)NB * 4);
  int2*  edges     = (int2*)alloc((size_t)NE * 8);
  int*   bounds    = (int*)alloc((size_t)(GG + 1) * 4);

  // W preps + setup (zero deg/pool, seg bounds) in ONE launch
  head_kernel<<<WCB + NB, 256, 0, stream>>>(
      g1_wl, g1_wr, g2_wl, g2_wr, wt1, wt2, batch, deg, pool, bounds);

  // CSR build: degree -> hierarchical scan -> fill (proven chain)
  degree_kernel<<<(NE + 255) / 256, 256, 0, stream>>>(ei, deg);
  blocksum_kernel<<<NB, 256, 0, stream>>>(deg, bsum);
  blockscan_kernel<<<1, 256, 0, stream>>>(bsum, bpre, rowstart);
  rowstart_kernel<<<NB, 256, 0, stream>>>(deg, bpre, rowstart, cursor);
  fill_kernel<<<(NE + 255) / 256, 256, 0, stream>>>(ei, ea, cursor, edges);

  const int MMB = ((NN + 127) / 128) * 4;   // 1564 matmul blocks

  // ---- GAT layer 1 (K=64): matmul WITH fused encoder, then edge phase ----
  matmul_enc_kernel<<<MMB, 256, 0, stream>>>(x, enc_w, enc_b, wt1, g1_bl,
                                             xl, xr, NN);
  gat_fused_kernel<<<NN / 4, 256, 0, stream>>>(rowstart, edges, xl, xr,
                                               g1_we, g1_att, g1_b, hb16);

  // ---- GAT layer 2 (K=256): matmul, then edge phase (bf16 out -> pooling) ----
  matmul_mfma_kernel<256><<<MMB, 256, 0, stream>>>(hb16, wt2, g2_bl, xl, xr, NN);
  gat_fused_kernel<<<NN / 4, 256, 0, stream>>>(rowstart, edges, xl, xr,
                                               g2_we, g2_att, g2_b, hb16);

  // ---- pooling (bf16 in) + MLP head ----
  pool_kernel<<<(NN + 63) / 64, 256, 0, stream>>>(hb16, batch, pool);
  mlp_kernel<<<GG, 128, 0, stream>>>(pool, bounds, p1_w, p1_b, ln_g, ln_b,
                                     p2_w, p2_b, head_w, head_b, out);
}

// Round 7
// 314.482 us; speedup vs baseline: 1.0570x; 1.0570x over previous
//
#include <hip/hip_runtime.h>
#include <hip/hip_bf16.h>
#include <math.h>

#define NN 50000     // nodes
#define NE 400000    // edges
#define HH 4         // heads
#define CC 64        // per-head dim
#define HC 256       // H*C
#define GG 64        // graphs
#define NB 196       // scan blocks: ceil(NN/256)
#define ENCB 12500   // encoder blocks
#define WCB 640      // wconv blocks

typedef short v8s __attribute__((ext_vector_type(8)));
typedef float f32x4 __attribute__((ext_vector_type(4)));

static __device__ inline unsigned short f2bf(float v) {
  __hip_bfloat16 b = __float2bfloat16(v);
  return *reinterpret_cast<unsigned short*>(&b);
}
// packed bf16 pair -> f32 (bf16 value = bit pattern << 16)
static __device__ inline float bflo(unsigned u) { return __uint_as_float(u << 16); }
static __device__ inline float bfhi(unsigned u) { return __uint_as_float(u & 0xffff0000u); }

// width-16 xor-butterfly step via ds_swizzle BitMode: ONE DS instr, no VALU
// addr math. offset = (xor<<10)|0x1F.
static __device__ inline float swz_xor(float v, int imm) {
  switch (imm) {
    case 8: return __int_as_float(__builtin_amdgcn_ds_swizzle(__float_as_int(v), 0x201F));
    case 4: return __int_as_float(__builtin_amdgcn_ds_swizzle(__float_as_int(v), 0x101F));
    case 2: return __int_as_float(__builtin_amdgcn_ds_swizzle(__float_as_int(v), 0x081F));
    default: return __int_as_float(__builtin_amdgcn_ds_swizzle(__float_as_int(v), 0x041F));
  }
}

// async global->LDS, 16B per lane. LDS dest is wave-uniform base + lane*16.
static __device__ inline void gload_lds16(const void* g, void* l) {
  __builtin_amdgcn_global_load_lds(
      (const __attribute__((address_space(1))) void*)g,
      (__attribute__((address_space(3))) void*)l, 16, 0, 0);
}

// ---- head kernel: encoder + all 4 W preps + setup, region-dispatched ----
// bid <  ENCB               : encoder  h0 = relu(x @ enc_w + enc_b) -> bf16
// bid <  ENCB+WCB           : wconv    W[K,256] f32 -> Wt bf16 [256][K]
// bid <  ENCB+WCB+NB        : setup    zero deg, zero pool, seg bounds
__global__ __launch_bounds__(256) void head_kernel(
    const float* __restrict__ x, const float* __restrict__ enc_w,
    const float* __restrict__ enc_b, unsigned short* __restrict__ h0,
    const float* __restrict__ g1_wl, const float* __restrict__ g1_wr,
    const float* __restrict__ g2_wl, const float* __restrict__ g2_wr,
    unsigned short* __restrict__ wt1, unsigned short* __restrict__ wt2,
    const int* __restrict__ batch, int* __restrict__ deg,
    float* __restrict__ pool, int* __restrict__ bounds) {
  int bid = blockIdx.x, tid = threadIdx.x;
  if (bid < ENCB) {
    int idx = bid * 256 + tid;
    int node = idx >> 6, col = idx & 63;
    const float* xr = x + node * 8;
    float acc = enc_b[col];
#pragma unroll
    for (int k = 0; k < 8; ++k) acc += xr[k] * enc_w[k * 64 + col];
    h0[idx] = f2bf(fmaxf(acc, 0.f));
  } else if (bid < ENCB + WCB) {
    int idx = (bid - ENCB) * 256 + tid;
    const float* W; unsigned short* Wt; int K; int base;
    if (idx < 16384)        { W = g1_wl; Wt = wt1;                     K = 64;  base = idx; }
    else if (idx < 32768)   { W = g1_wr; Wt = wt1 + (size_t)256 * 64;  K = 64;  base = idx - 16384; }
    else if (idx < 98304)   { W = g2_wl; Wt = wt2;                     K = 256; base = idx - 32768; }
    else if (idx < 163840)  { W = g2_wr; Wt = wt2 + (size_t)256 * 256; K = 256; base = idx - 98304; }
    else return;
    int k = base >> 8, n = base & 255;
    Wt[n * K + k] = f2bf(W[base]);
  } else {
    int sb = bid - ENCB - WCB;           // 0..NB-1
    int i = sb * 256 + tid;
    if (i < NN) deg[i] = 0;
    if (sb < GG) pool[sb * 256 + tid] = 0.f;
    if (sb == NB - 1 && tid <= GG) {
      int g = tid, lo = 0, hi = NN;
      while (lo < hi) {
        int mid = (lo + hi) >> 1;
        if (batch[mid] < g) lo = mid + 1; else hi = mid;
      }
      bounds[g] = lo;
    }
  }
}

// ------- MFMA matmul: {xl,xr}(bf16)[M,256] = A(bf16) @ [Wl;Wr] (bias on xl) -------
// 2-phase double-buffered pipeline (T3-minimum), global_load_lds w16, swizzled.
template <int K>
__global__ __launch_bounds__(256) void matmul_mfma_kernel(
    const unsigned short* __restrict__ A, const unsigned short* __restrict__ Wt,
    const float* __restrict__ bias,
    unsigned short* __restrict__ outL, unsigned short* __restrict__ outR, int M) {
  const int mmb = ((M + 127) >> 7) << 2;
  int bid = blockIdx.x;
  {
    int q = mmb >> 3, r = mmb & 7;
    int xcd = bid & 7, off2 = bid >> 3;
    bid = (xcd < r ? xcd * (q + 1) : r * (q + 1) + (xcd - r) * q) + off2;
  }
  __shared__ __attribute__((aligned(16))) unsigned short lds[16384];
  const int tid = threadIdx.x;
  const int wave = tid >> 6;
  const int lane = tid & 63;
  const int quad = lane >> 4;
  const int lrow = lane & 15;
  const int wr = (wave & 1) * 64;
  const int wc = (wave >> 1) * 64;
  const int r0 = (bid >> 2) * 128;
  const int n0 = (bid & 3) * 128;

  f32x4 acc[4][4];
#pragma unroll
  for (int i = 0; i < 4; ++i)
#pragma unroll
    for (int j = 0; j < 4; ++j) acc[i][j] = (f32x4){0.f, 0.f, 0.f, 0.f};

  const int lrA0 = (wave * 2) * 16 + (lane >> 2);
  const int lrA1 = lrA0 + 16;
  const int c    = lane & 3;
  const int cs0  = c ^ ((lrA0 >> 1) & 3);
  const int cs1  = c ^ ((lrA1 >> 1) & 3);
  int ga0 = r0 + lrA0; if (ga0 >= M) ga0 = M - 1;
  int ga1 = r0 + lrA1; if (ga1 >= M) ga1 = M - 1;
  const unsigned short* srcA0 = A  + (size_t)ga0 * K + cs0 * 8;
  const unsigned short* srcA1 = A  + (size_t)ga1 * K + cs1 * 8;
  const unsigned short* srcB0 = Wt + (size_t)(n0 + lrA0) * K + cs0 * 8;
  const unsigned short* srcB1 = Wt + (size_t)(n0 + lrA1) * K + cs1 * 8;
  const int doff0 = (wave * 2 + 0) * 512;
  const int doff1 = (wave * 2 + 1) * 512;
  const int qsw = (quad ^ ((lrow >> 1) & 3)) * 8;

  constexpr int NT = K / 32;
  gload_lds16(srcA0, &lds[doff0]);
  gload_lds16(srcA1, &lds[doff1]);
  gload_lds16(srcB0, &lds[4096 + doff0]);
  gload_lds16(srcB1, &lds[4096 + doff1]);
  __syncthreads();

  int cur = 0;
#pragma unroll
  for (int t = 0; t < NT; ++t) {
    if (t + 1 < NT) {
      const int k0 = (t + 1) * 32;
      const int nb = (cur ^ 1) * 8192;
      gload_lds16(srcA0 + k0, &lds[nb + doff0]);
      gload_lds16(srcA1 + k0, &lds[nb + doff1]);
      gload_lds16(srcB0 + k0, &lds[nb + 4096 + doff0]);
      gload_lds16(srcB1 + k0, &lds[nb + 4096 + doff1]);
    }
    const unsigned short* base = &lds[cur * 8192];
    v8s af[4], bf[4];
#pragma unroll
    for (int rt = 0; rt < 4; ++rt)
      af[rt] = *(const v8s*)&base[(wr + rt * 16 + lrow) * 32 + qsw];
#pragma unroll
    for (int ct = 0; ct < 4; ++ct)
      bf[ct] = *(const v8s*)&base[4096 + (wc + ct * 16 + lrow) * 32 + qsw];
#pragma unroll
    for (int rt = 0; rt < 4; ++rt)
#pragma unroll
      for (int ct = 0; ct < 4; ++ct)
        acc[rt][ct] = __builtin_amdgcn_mfma_f32_16x16x32_bf16(af[rt], bf[ct], acc[rt][ct], 0, 0, 0);
    __syncthreads();
    cur ^= 1;
  }

  const bool isL = (n0 < 256);
  unsigned short* outp = isL ? outL : outR;
  const int cbase = isL ? n0 : (n0 - 256);
  constexpr int SP = 136;
  unsigned short* stage = lds;

#pragma unroll
  for (int rt = 0; rt < 4; ++rt) {
    __syncthreads();
#pragma unroll
    for (int ct = 0; ct < 4; ++ct) {
      int col = wc + ct * 16 + lrow;
      float b = isL ? bias[cbase + col] : 0.f;
#pragma unroll
      for (int r = 0; r < 4; ++r) {
        int sr = (wave & 1) * 16 + quad * 4 + r;
        stage[sr * SP + col] = f2bf(acc[rt][ct][r] + b);
      }
    }
    __syncthreads();
    int sr = tid >> 3;
    int c0 = (tid & 7) * 16;
    int grow = r0 + (sr >> 4) * 64 + rt * 16 + (sr & 15);
    if (grow < M) {
      uint4 v0 = *(const uint4*)&stage[sr * SP + c0];
      uint4 v1 = *(const uint4*)&stage[sr * SP + c0 + 8];
      *(uint4*)&outp[(size_t)grow * 256 + cbase + c0] = v0;
      *(uint4*)&outp[(size_t)grow * 256 + cbase + c0 + 8] = v1;
    }
  }
}

// ---------------- CSR build (proven 3-kernel scan chain) ----------------
__global__ void degree_kernel(const int* __restrict__ ei, int* __restrict__ deg) {
  int e = blockIdx.x * 256 + threadIdx.x;
  if (e < NE) atomicAdd(&deg[ei[NE + e]], 1);
}

__global__ __launch_bounds__(256) void blocksum_kernel(
    const int* __restrict__ deg, int* __restrict__ bsum) {
  int t = threadIdx.x;
  int i = blockIdx.x * 256 + t;
  int v = (i < NN) ? deg[i] : 0;
#pragma unroll
  for (int off = 32; off; off >>= 1) v += __shfl_down(v, off, 64);
  __shared__ int ws[4];
  if ((t & 63) == 0) ws[t >> 6] = v;
  __syncthreads();
  if (t == 0) bsum[blockIdx.x] = ws[0] + ws[1] + ws[2] + ws[3];
}

__global__ __launch_bounds__(256) void blockscan_kernel(
    const int* __restrict__ bsum, int* __restrict__ bpre, int* __restrict__ rowstart) {
  __shared__ int s[256];
  int t = threadIdx.x;
  int v = (t < NB) ? bsum[t] : 0;
  s[t] = v;
  __syncthreads();
  for (int off = 1; off < 256; off <<= 1) {
    int x = s[t];
    int y = (t >= off) ? s[t - off] : 0;
    __syncthreads();
    s[t] = x + y;
    __syncthreads();
  }
  if (t < NB) bpre[t] = s[t] - v;
  if (t == 255) rowstart[NN] = s[255];
}

__global__ __launch_bounds__(256) void rowstart_kernel(
    const int* __restrict__ deg, const int* __restrict__ bpre,
    int* __restrict__ rowstart, int* __restrict__ cursor) {
  __shared__ int s[256];
  int t = threadIdx.x;
  int i = blockIdx.x * 256 + t;
  int v = (i < NN) ? deg[i] : 0;
  s[t] = v;
  __syncthreads();
  for (int off = 1; off < 256; off <<= 1) {
    int x = s[t];
    int y = (t >= off) ? s[t - off] : 0;
    __syncthreads();
    s[t] = x + y;
    __syncthreads();
  }
  if (i < NN) {
    int rs = bpre[blockIdx.x] + s[t] - v;
    rowstart[i] = rs;
    cursor[i] = rs;
  }
}

// CSR fill: int2 (src BYTE OFFSET = src*512, ea-bits) -> one aligned 8B store.
__global__ void fill_kernel(const int* __restrict__ ei, const float* __restrict__ ea,
                            int* __restrict__ cursor, int2* __restrict__ edges) {
  int e = blockIdx.x * 256 + threadIdx.x;
  if (e < NE) {
    int d = ei[NE + e];
    int pos = atomicAdd(&cursor[d], 1);
    edges[pos] = make_int2(ei[e] << 9, __float_as_int(ea[e]));
  }
}

// ---------------- fused GATv2 edge phase: wave per dst node (r4 body) ----
// POOL=true (layer 2): skip the hb16 write; instead stage each wave's
// bf16-rounded output in LDS and flush per-block to pool[] (1 atomic set per
// block when the 4 nodes share a graph -- batch is sorted so ~98% do).
// Summands are bitwise-identical to pool_kernel's (bflo(f2bf(o))); only the
// (already nondeterministic) atomic order changes.
template <bool POOL>
__global__ __launch_bounds__(256) void gat_fused_kernel(
    const int* __restrict__ rowstart, const int2* __restrict__ edges,
    const unsigned short* __restrict__ xl, const unsigned short* __restrict__ xr,
    const float* __restrict__ we, const float* __restrict__ att,
    const float* __restrict__ bias, unsigned short* __restrict__ outb,
    const int* __restrict__ batch, float* __restrict__ pool) {
  __shared__ float pacc[4][256];
  __shared__ int pb[4];
  int tid = threadIdx.x;
  int node = (blockIdx.x * 256 + tid) >> 6;
  int lane = tid & 63;
  int wave = tid >> 6;
  int r0 = __builtin_amdgcn_readfirstlane(rowstart[node]);
  int r1 = __builtin_amdgcn_readfirstlane(rowstart[node + 1]);
  if (POOL && lane == 0) pb[wave] = batch[node];
  const char* xlb = (const char*)xl;          // UNIFORM gather base
  const unsigned lane8 = (unsigned)lane * 8u;
  uint2 rp = ((const uint2*)xr)[(size_t)node * 64 + lane];
  float4 r = make_float4(bflo(rp.x), bfhi(rp.x), bflo(rp.y), bfhi(rp.y));
  float4 wv = ((const float4*)we)[lane];
  float4 at = ((const float4*)att)[lane];
  const float LOG2E = 1.442695040888963f;
  at.x *= LOG2E; at.y *= LOG2E; at.z *= LOG2E; at.w *= LOG2E;
  float4 acc = make_float4(0.f, 0.f, 0.f, 0.f);
  float denom = 0.f;

  auto edge_step = [&](float eav, uint2 p) {
    float4 a = make_float4(bflo(p.x), bfhi(p.x), bflo(p.y), bfhi(p.y));
    float s0 = a.x + (r.x + eav * wv.x);
    float s1 = a.y + (r.y + eav * wv.y);
    float s2 = a.z + (r.z + eav * wv.z);
    float s3 = a.w + (r.w + eav * wv.w);
    s0 = fmaxf(s0, 0.2f * s0);
    s1 = fmaxf(s1, 0.2f * s1);
    s2 = fmaxf(s2, 0.2f * s2);
    s3 = fmaxf(s3, 0.2f * s3);
    float p4 = (s0 * at.x + s1 * at.y) + (s2 * at.z + s3 * at.w);
    p4 += swz_xor(p4, 8);
    p4 += swz_xor(p4, 4);
    p4 += swz_xor(p4, 2);
    p4 += swz_xor(p4, 1);
    float ex = exp2f(p4);
    denom += ex;
    acc.x += ex * a.x; acc.y += ex * a.y; acc.z += ex * a.z; acc.w += ex * a.w;
  };
  auto gath = [&](int byteoff) {
    return *(const uint2*)(xlb + (unsigned)byteoff + lane8);
  };

  int i = r0;
  if (i + 8 <= r1) {
    int2 e0 = edges[i];     int2 e1 = edges[i + 1];
    int2 e2 = edges[i + 2]; int2 e3 = edges[i + 3];
    uint2 p0 = gath(e0.x), p1 = gath(e1.x), p2 = gath(e2.x), p3 = gath(e3.x);
    for (; i + 8 <= r1; i += 4) {
      int2 f0 = edges[i + 4]; int2 f1 = edges[i + 5];
      int2 f2 = edges[i + 6]; int2 f3 = edges[i + 7];
      uint2 q0 = gath(f0.x), q1 = gath(f1.x), q2 = gath(f2.x), q3 = gath(f3.x);
      edge_step(__int_as_float(e0.y), p0);
      edge_step(__int_as_float(e1.y), p1);
      edge_step(__int_as_float(e2.y), p2);
      edge_step(__int_as_float(e3.y), p3);
      e0 = f0; e1 = f1; e2 = f2; e3 = f3;
      p0 = q0; p1 = q1; p2 = q2; p3 = q3;
    }
    edge_step(__int_as_float(e0.y), p0);
    edge_step(__int_as_float(e1.y), p1);
    edge_step(__int_as_float(e2.y), p2);
    edge_step(__int_as_float(e3.y), p3);
    i += 4;
  } else if (i + 4 <= r1) {
    int2 e0 = edges[i];     int2 e1 = edges[i + 1];
    int2 e2 = edges[i + 2]; int2 e3 = edges[i + 3];
    uint2 p0 = gath(e0.x), p1 = gath(e1.x), p2 = gath(e2.x), p3 = gath(e3.x);
    edge_step(__int_as_float(e0.y), p0);
    edge_step(__int_as_float(e1.y), p1);
    edge_step(__int_as_float(e2.y), p2);
    edge_step(__int_as_float(e3.y), p3);
    i += 4;
  }
  for (; i < r1; ++i) {
    int2 e = edges[i];
    edge_step(__int_as_float(e.y), gath(e.x));
  }

  float inv = 1.f / (denom + 1e-16f);
  float4 bv = ((const float4*)bias)[lane];
  float4 o;
  o.x = fmaxf(acc.x * inv + bv.x, 0.f);
  o.y = fmaxf(acc.y * inv + bv.y, 0.f);
  o.z = fmaxf(acc.z * inv + bv.z, 0.f);
  o.w = fmaxf(acc.w * inv + bv.w, 0.f);
  uint2 pk;
  pk.x = (unsigned)f2bf(o.x) | ((unsigned)f2bf(o.y) << 16);
  pk.y = (unsigned)f2bf(o.z) | ((unsigned)f2bf(o.w) << 16);
  if constexpr (!POOL) {
    ((uint2*)outb)[(size_t)node * 64 + lane] = pk;
  } else {
    // bf16-rounded f32 values (bitwise = pool_kernel's summands)
    *(float4*)&pacc[wave][lane * 4] =
        make_float4(bflo(pk.x), bfhi(pk.x), bflo(pk.y), bfhi(pk.y));
    __syncthreads();
    int b0 = pb[0], b1 = pb[1], b2 = pb[2], b3 = pb[3];
    if (b0 == b1 && b1 == b2 && b2 == b3) {
      float s = (pacc[0][tid] + pacc[1][tid]) + (pacc[2][tid] + pacc[3][tid]);
      atomicAdd(&pool[b0 * 256 + tid], s);
    } else {
      atomicAdd(&pool[b0 * 256 + tid], pacc[0][tid]);
      atomicAdd(&pool[b1 * 256 + tid], pacc[1][tid]);
      atomicAdd(&pool[b2 * 256 + tid], pacc[2][tid]);
      atomicAdd(&pool[b3 * 256 + tid], pacc[3][tid]);
    }
  }
}

// ---------------- final MLP: one block (128 thr) per graph ----------------
__global__ __launch_bounds__(128) void mlp_kernel(
    const float* __restrict__ pool, const int* __restrict__ bounds,
    const float* __restrict__ p1w, const float* __restrict__ p1b,
    const float* __restrict__ lng, const float* __restrict__ lnb,
    const float* __restrict__ p2w, const float* __restrict__ p2b,
    const float* __restrict__ hw, const float* __restrict__ hb,
    float* __restrict__ out) {
  __shared__ float sg[256];
  __shared__ float red[128];
  __shared__ float sz[128];
  __shared__ float s2[64];
  int b = blockIdx.x, tid = threadIdx.x;
  float cntf = (float)(bounds[b + 1] - bounds[b]);
  float invc = 1.f / fmaxf(cntf, 1.f);
  for (int i = tid; i < 256; i += 128) sg[i] = pool[b * 256 + i] * invc;
  __syncthreads();
  float z = p1b[tid];
  for (int k = 0; k < 256; ++k) z += sg[k] * p1w[k * 128 + tid];
  red[tid] = z; __syncthreads();
  for (int off = 64; off; off >>= 1) { if (tid < off) red[tid] += red[tid + off]; __syncthreads(); }
  float mu = red[0] * (1.f / 128.f);
  __syncthreads();
  float d = z - mu;
  red[tid] = d * d; __syncthreads();
  for (int off = 64; off; off >>= 1) { if (tid < off) red[tid] += red[tid + off]; __syncthreads(); }
  float var = red[0] * (1.f / 128.f);
  float zn = d * rsqrtf(var + 1e-5f) * lng[tid] + lnb[tid];
  sz[tid] = fmaxf(zn, 0.f);
  __syncthreads();
  if (tid < 64) {
    float a = p2b[tid];
    for (int k = 0; k < 128; ++k) a += sz[k] * p2w[k * 64 + tid];
    s2[tid] = fmaxf(a, 0.f);
  }
  __syncthreads();
  if (tid < 64) {
    float p = s2[tid] * hw[tid];
    for (int off = 32; off; off >>= 1) p += __shfl_down(p, off, 64);
    if (tid == 0) out[b] = p + hb[0];
  }
}

extern "C" void kernel_launch(void* const* d_in, const int* in_sizes, int n_in,
                              void* d_out, int out_size, void* d_ws, size_t ws_size,
                              hipStream_t stream) {
  const float* x      = (const float*)d_in[0];
  const int*   ei     = (const int*)d_in[1];
  const float* ea     = (const float*)d_in[2];
  const int*   batch  = (const int*)d_in[3];
  const float* enc_w  = (const float*)d_in[4];
  const float* enc_b  = (const float*)d_in[5];
  const float* g1_wl  = (const float*)d_in[6];
  const float* g1_bl  = (const float*)d_in[7];
  const float* g1_wr  = (const float*)d_in[8];
  const float* g1_we  = (const float*)d_in[9];
  const float* g1_att = (const float*)d_in[10];
  const float* g1_b   = (const float*)d_in[11];
  const float* g2_wl  = (const float*)d_in[12];
  const float* g2_bl  = (const float*)d_in[13];
  const float* g2_wr  = (const float*)d_in[14];
  const float* g2_we  = (const float*)d_in[15];
  const float* g2_att = (const float*)d_in[16];
  const float* g2_b   = (const float*)d_in[17];
  const float* p1_w   = (const float*)d_in[18];
  const float* p1_b   = (const float*)d_in[19];
  const float* ln_g   = (const float*)d_in[20];
  const float* ln_b   = (const float*)d_in[21];
  const float* p2_w   = (const float*)d_in[22];
  const float* p2_b   = (const float*)d_in[23];
  const float* head_w = (const float*)d_in[24];
  const float* head_b = (const float*)d_in[25];
  float* out = (float*)d_out;

  char* ws = (char*)d_ws;
  size_t off = 0;
  auto alloc = [&](size_t bytes) -> void* {
    void* p = ws + off;
    off = (off + bytes + 255) & ~(size_t)255;
    return p;
  };
  unsigned short* xl   = (unsigned short*)alloc((size_t)NN * HC * 2);
  unsigned short* xr   = (unsigned short*)alloc((size_t)NN * HC * 2);
  unsigned short* h0   = (unsigned short*)alloc((size_t)NN * 64 * 2);
  unsigned short* hb16 = (unsigned short*)alloc((size_t)NN * HC * 2);
  unsigned short* wt1  = (unsigned short*)alloc((size_t)512 * 64 * 2);
  unsigned short* wt2  = (unsigned short*)alloc((size_t)512 * 256 * 2);
  float* pool      = (float*)alloc((size_t)GG * HC * 4);
  int*   deg       = (int*)alloc((size_t)NN * 4);
  int*   rowstart  = (int*)alloc((size_t)(NN + 1) * 4);
  int*   cursor    = (int*)alloc((size_t)NN * 4);
  int*   bsum      = (int*)alloc((size_t)NB * 4);
  int*   bpre      = (int*)alloc((size_t)NB * 4);
  int2*  edges     = (int2*)alloc((size_t)NE * 8);
  int*   bounds    = (int*)alloc((size_t)(GG + 1) * 4);

  // encoder + weight prep + setup (zero deg/pool, seg bounds) in ONE launch
  head_kernel<<<ENCB + WCB + NB, 256, 0, stream>>>(
      x, enc_w, enc_b, h0, g1_wl, g1_wr, g2_wl, g2_wr, wt1, wt2,
      batch, deg, pool, bounds);

  // CSR build: degree -> hierarchical scan -> fill (proven chain)
  degree_kernel<<<(NE + 255) / 256, 256, 0, stream>>>(ei, deg);
  blocksum_kernel<<<NB, 256, 0, stream>>>(deg, bsum);
  blockscan_kernel<<<1, 256, 0, stream>>>(bsum, bpre, rowstart);
  rowstart_kernel<<<NB, 256, 0, stream>>>(deg, bpre, rowstart, cursor);
  fill_kernel<<<(NE + 255) / 256, 256, 0, stream>>>(ei, ea, cursor, edges);

  const int MMB = ((NN + 127) / 128) * 4;   // 1564 matmul blocks

  // ---- GAT layer 1 (K=64): matmul -> xl/xr, then edge phase ----
  matmul_mfma_kernel<64><<<MMB, 256, 0, stream>>>(h0, wt1, g1_bl, xl, xr, NN);
  gat_fused_kernel<false><<<NN / 4, 256, 0, stream>>>(
      rowstart, edges, xl, xr, g1_we, g1_att, g1_b, hb16, batch, pool);

  // ---- GAT layer 2 (K=256): matmul, then edge phase (pool fused in) ----
  matmul_mfma_kernel<256><<<MMB, 256, 0, stream>>>(hb16, wt2, g2_bl, xl, xr, NN);
  gat_fused_kernel<true><<<NN / 4, 256, 0, stream>>>(
      rowstart, edges, xl, xr, g2_we, g2_att, g2_b, nullptr, batch, pool);

  // ---- MLP head (pool already accumulated by gat2) ----
  mlp_kernel<<<GG, 128, 0, stream>>>(pool, bounds, p1_w, p1_b, ln_g, ln_b,
                                     p2_w, p2_b, head_w, head_b, out);
}

// Round 8
// 314.099 us; speedup vs baseline: 1.0583x; 1.0012x over previous
//
#include <hip/hip_runtime.h>
#include <hip/hip_bf16.h>
#include <math.h>

#define NN 50000     // nodes
#define NE 400000    // edges
#define HH 4         // heads
#define CC 64        // per-head dim
#define HC 256       // H*C
#define GG 64        // graphs
#define NB 196       // scan blocks: ceil(NN/256)
#define ENCB 12500   // encoder blocks
#define WCB 640      // wconv blocks

typedef short v8s __attribute__((ext_vector_type(8)));
typedef float f32x4 __attribute__((ext_vector_type(4)));

static __device__ inline unsigned short f2bf(float v) {
  __hip_bfloat16 b = __float2bfloat16(v);
  return *reinterpret_cast<unsigned short*>(&b);
}
// packed bf16 pair -> f32 (bf16 value = bit pattern << 16)
static __device__ inline float bflo(unsigned u) { return __uint_as_float(u << 16); }
static __device__ inline float bfhi(unsigned u) { return __uint_as_float(u & 0xffff0000u); }

// width-16 xor-butterfly step via ds_swizzle BitMode: ONE DS instr, no VALU
// addr math. offset = (xor<<10)|0x1F.
static __device__ inline float swz_xor(float v, int imm) {
  switch (imm) {
    case 8: return __int_as_float(__builtin_amdgcn_ds_swizzle(__float_as_int(v), 0x201F));
    case 4: return __int_as_float(__builtin_amdgcn_ds_swizzle(__float_as_int(v), 0x101F));
    case 2: return __int_as_float(__builtin_amdgcn_ds_swizzle(__float_as_int(v), 0x081F));
    default: return __int_as_float(__builtin_amdgcn_ds_swizzle(__float_as_int(v), 0x041F));
  }
}

// async global->LDS, 16B per lane. LDS dest is wave-uniform base + lane*16.
static __device__ inline void gload_lds16(const void* g, void* l) {
  __builtin_amdgcn_global_load_lds(
      (const __attribute__((address_space(1))) void*)g,
      (__attribute__((address_space(3))) void*)l, 16, 0, 0);
}

// ---- head kernel: encoder + all 4 W preps + setup, region-dispatched ----
// bid <  ENCB               : encoder  h0 = relu(x @ enc_w + enc_b) -> bf16
// bid <  ENCB+WCB           : wconv    W[K,256] f32 -> Wt bf16 [256][K]
// bid <  ENCB+WCB+NB        : setup    zero deg, zero pool, seg bounds
__global__ __launch_bounds__(256) void head_kernel(
    const float* __restrict__ x, const float* __restrict__ enc_w,
    const float* __restrict__ enc_b, unsigned short* __restrict__ h0,
    const float* __restrict__ g1_wl, const float* __restrict__ g1_wr,
    const float* __restrict__ g2_wl, const float* __restrict__ g2_wr,
    unsigned short* __restrict__ wt1, unsigned short* __restrict__ wt2,
    const int* __restrict__ batch, int* __restrict__ deg,
    float* __restrict__ pool, int* __restrict__ bounds) {
  int bid = blockIdx.x, tid = threadIdx.x;
  if (bid < ENCB) {
    int idx = bid * 256 + tid;
    int node = idx >> 6, col = idx & 63;
    const float* xr = x + node * 8;
    float acc = enc_b[col];
#pragma unroll
    for (int k = 0; k < 8; ++k) acc += xr[k] * enc_w[k * 64 + col];
    h0[idx] = f2bf(fmaxf(acc, 0.f));
  } else if (bid < ENCB + WCB) {
    int idx = (bid - ENCB) * 256 + tid;
    const float* W; unsigned short* Wt; int K; int base;
    if (idx < 16384)        { W = g1_wl; Wt = wt1;                     K = 64;  base = idx; }
    else if (idx < 32768)   { W = g1_wr; Wt = wt1 + (size_t)256 * 64;  K = 64;  base = idx - 16384; }
    else if (idx < 98304)   { W = g2_wl; Wt = wt2;                     K = 256; base = idx - 32768; }
    else if (idx < 163840)  { W = g2_wr; Wt = wt2 + (size_t)256 * 256; K = 256; base = idx - 98304; }
    else return;
    int k = base >> 8, n = base & 255;
    Wt[n * K + k] = f2bf(W[base]);
  } else {
    int sb = bid - ENCB - WCB;           // 0..NB-1
    int i = sb * 256 + tid;
    if (i < NN) deg[i] = 0;
    if (sb < GG) pool[sb * 256 + tid] = 0.f;
    if (sb == NB - 1 && tid <= GG) {
      int g = tid, lo = 0, hi = NN;
      while (lo < hi) {
        int mid = (lo + hi) >> 1;
        if (batch[mid] < g) lo = mid + 1; else hi = mid;
      }
      bounds[g] = lo;
    }
  }
}

// ------- MFMA matmul: {xl,xr}(bf16)[M,256] = A(bf16) @ [Wl;Wr] (bias on xl) -------
// 2-phase double-buffered pipeline (T3-minimum), global_load_lds w16, swizzled.
template <int K>
__global__ __launch_bounds__(256) void matmul_mfma_kernel(
    const unsigned short* __restrict__ A, const unsigned short* __restrict__ Wt,
    const float* __restrict__ bias,
    unsigned short* __restrict__ outL, unsigned short* __restrict__ outR, int M) {
  const int mmb = ((M + 127) >> 7) << 2;
  int bid = blockIdx.x;
  {
    int q = mmb >> 3, r = mmb & 7;
    int xcd = bid & 7, off2 = bid >> 3;
    bid = (xcd < r ? xcd * (q + 1) : r * (q + 1) + (xcd - r) * q) + off2;
  }
  __shared__ __attribute__((aligned(16))) unsigned short lds[16384];
  const int tid = threadIdx.x;
  const int wave = tid >> 6;
  const int lane = tid & 63;
  const int quad = lane >> 4;
  const int lrow = lane & 15;
  const int wr = (wave & 1) * 64;
  const int wc = (wave >> 1) * 64;
  const int r0 = (bid >> 2) * 128;
  const int n0 = (bid & 3) * 128;

  f32x4 acc[4][4];
#pragma unroll
  for (int i = 0; i < 4; ++i)
#pragma unroll
    for (int j = 0; j < 4; ++j) acc[i][j] = (f32x4){0.f, 0.f, 0.f, 0.f};

  const int lrA0 = (wave * 2) * 16 + (lane >> 2);
  const int lrA1 = lrA0 + 16;
  const int c    = lane & 3;
  const int cs0  = c ^ ((lrA0 >> 1) & 3);
  const int cs1  = c ^ ((lrA1 >> 1) & 3);
  int ga0 = r0 + lrA0; if (ga0 >= M) ga0 = M - 1;
  int ga1 = r0 + lrA1; if (ga1 >= M) ga1 = M - 1;
  const unsigned short* srcA0 = A  + (size_t)ga0 * K + cs0 * 8;
  const unsigned short* srcA1 = A  + (size_t)ga1 * K + cs1 * 8;
  const unsigned short* srcB0 = Wt + (size_t)(n0 + lrA0) * K + cs0 * 8;
  const unsigned short* srcB1 = Wt + (size_t)(n0 + lrA1) * K + cs1 * 8;
  const int doff0 = (wave * 2 + 0) * 512;
  const int doff1 = (wave * 2 + 1) * 512;
  const int qsw = (quad ^ ((lrow >> 1) & 3)) * 8;

  constexpr int NT = K / 32;
  gload_lds16(srcA0, &lds[doff0]);
  gload_lds16(srcA1, &lds[doff1]);
  gload_lds16(srcB0, &lds[4096 + doff0]);
  gload_lds16(srcB1, &lds[4096 + doff1]);
  __syncthreads();

  int cur = 0;
#pragma unroll
  for (int t = 0; t < NT; ++t) {
    if (t + 1 < NT) {
      const int k0 = (t + 1) * 32;
      const int nb = (cur ^ 1) * 8192;
      gload_lds16(srcA0 + k0, &lds[nb + doff0]);
      gload_lds16(srcA1 + k0, &lds[nb + doff1]);
      gload_lds16(srcB0 + k0, &lds[nb + 4096 + doff0]);
      gload_lds16(srcB1 + k0, &lds[nb + 4096 + doff1]);
    }
    const unsigned short* base = &lds[cur * 8192];
    v8s af[4], bf[4];
#pragma unroll
    for (int rt = 0; rt < 4; ++rt)
      af[rt] = *(const v8s*)&base[(wr + rt * 16 + lrow) * 32 + qsw];
#pragma unroll
    for (int ct = 0; ct < 4; ++ct)
      bf[ct] = *(const v8s*)&base[4096 + (wc + ct * 16 + lrow) * 32 + qsw];
#pragma unroll
    for (int rt = 0; rt < 4; ++rt)
#pragma unroll
      for (int ct = 0; ct < 4; ++ct)
        acc[rt][ct] = __builtin_amdgcn_mfma_f32_16x16x32_bf16(af[rt], bf[ct], acc[rt][ct], 0, 0, 0);
    __syncthreads();
    cur ^= 1;
  }

  const bool isL = (n0 < 256);
  unsigned short* outp = isL ? outL : outR;
  const int cbase = isL ? n0 : (n0 - 256);
  constexpr int SP = 136;
  unsigned short* stage = lds;

#pragma unroll
  for (int rt = 0; rt < 4; ++rt) {
    __syncthreads();
#pragma unroll
    for (int ct = 0; ct < 4; ++ct) {
      int col = wc + ct * 16 + lrow;
      float b = isL ? bias[cbase + col] : 0.f;
#pragma unroll
      for (int r = 0; r < 4; ++r) {
        int sr = (wave & 1) * 16 + quad * 4 + r;
        stage[sr * SP + col] = f2bf(acc[rt][ct][r] + b);
      }
    }
    __syncthreads();
    int sr = tid >> 3;
    int c0 = (tid & 7) * 16;
    int grow = r0 + (sr >> 4) * 64 + rt * 16 + (sr & 15);
    if (grow < M) {
      uint4 v0 = *(const uint4*)&stage[sr * SP + c0];
      uint4 v1 = *(const uint4*)&stage[sr * SP + c0 + 8];
      *(uint4*)&outp[(size_t)grow * 256 + cbase + c0] = v0;
      *(uint4*)&outp[(size_t)grow * 256 + cbase + c0 + 8] = v1;
    }
  }
}

// ---------------- CSR build (proven 3-kernel scan chain) ----------------
__global__ void degree_kernel(const int* __restrict__ ei, int* __restrict__ deg) {
  int e = blockIdx.x * 256 + threadIdx.x;
  if (e < NE) atomicAdd(&deg[ei[NE + e]], 1);
}

__global__ __launch_bounds__(256) void blocksum_kernel(
    const int* __restrict__ deg, int* __restrict__ bsum) {
  int t = threadIdx.x;
  int i = blockIdx.x * 256 + t;
  int v = (i < NN) ? deg[i] : 0;
#pragma unroll
  for (int off = 32; off; off >>= 1) v += __shfl_down(v, off, 64);
  __shared__ int ws[4];
  if ((t & 63) == 0) ws[t >> 6] = v;
  __syncthreads();
  if (t == 0) bsum[blockIdx.x] = ws[0] + ws[1] + ws[2] + ws[3];
}

__global__ __launch_bounds__(256) void blockscan_kernel(
    const int* __restrict__ bsum, int* __restrict__ bpre, int* __restrict__ rowstart) {
  __shared__ int s[256];
  int t = threadIdx.x;
  int v = (t < NB) ? bsum[t] : 0;
  s[t] = v;
  __syncthreads();
  for (int off = 1; off < 256; off <<= 1) {
    int x = s[t];
    int y = (t >= off) ? s[t - off] : 0;
    __syncthreads();
    s[t] = x + y;
    __syncthreads();
  }
  if (t < NB) bpre[t] = s[t] - v;
  if (t == 255) rowstart[NN] = s[255];
}

__global__ __launch_bounds__(256) void rowstart_kernel(
    const int* __restrict__ deg, const int* __restrict__ bpre,
    int* __restrict__ rowstart, int* __restrict__ cursor) {
  __shared__ int s[256];
  int t = threadIdx.x;
  int i = blockIdx.x * 256 + t;
  int v = (i < NN) ? deg[i] : 0;
  s[t] = v;
  __syncthreads();
  for (int off = 1; off < 256; off <<= 1) {
    int x = s[t];
    int y = (t >= off) ? s[t - off] : 0;
    __syncthreads();
    s[t] = x + y;
    __syncthreads();
  }
  if (i < NN) {
    int rs = bpre[blockIdx.x] + s[t] - v;
    rowstart[i] = rs;
    cursor[i] = rs;
  }
}

// CSR fill: int2 (src BYTE OFFSET = src*512, ea-bits) -> one aligned 8B store.
__global__ void fill_kernel(const int* __restrict__ ei, const float* __restrict__ ea,
                            int* __restrict__ cursor, int2* __restrict__ edges) {
  int e = blockIdx.x * 256 + threadIdx.x;
  if (e < NE) {
    int d = ei[NE + e];
    int pos = atomicAdd(&cursor[d], 1);
    edges[pos] = make_int2(ei[e] << 9, __float_as_int(ea[e]));
  }
}

// ---------------- fused GATv2 edge phase: wave per dst node (r4 body) ----
// POOL=true (layer 2): skip the hb16 write; each wave stages its 256
// bf16-rounded outputs in LDS, fences, bumps a shared counter, and EXITS --
// only the last-arriving wave reduces the 4 slices and issues the atomics.
// No end-of-block __syncthreads => no max-of-4-degrees barrier tail (r7's
// +13us regression on gat2). Summands bitwise = pool_kernel's; atomic order
// was already nondeterministic.
template <bool POOL>
__global__ __launch_bounds__(256) void gat_fused_kernel(
    const int* __restrict__ rowstart, const int2* __restrict__ edges,
    const unsigned short* __restrict__ xl, const unsigned short* __restrict__ xr,
    const float* __restrict__ we, const float* __restrict__ att,
    const float* __restrict__ bias, unsigned short* __restrict__ outb,
    const int* __restrict__ batch, float* __restrict__ pool) {
  __shared__ float pacc[POOL ? 4 : 1][POOL ? 256 : 1];
  __shared__ int pb[4];
  __shared__ int done;
  int tid = threadIdx.x;
  int node = (blockIdx.x * 256 + tid) >> 6;
  int lane = tid & 63;
  int wave = tid >> 6;
  if constexpr (POOL) {
    if (tid == 0) done = 0;
    if (lane == 0) pb[wave] = batch[node];
    __syncthreads();                     // uniform start point: ~free; orders done=0
  }
  int r0 = __builtin_amdgcn_readfirstlane(rowstart[node]);
  int r1 = __builtin_amdgcn_readfirstlane(rowstart[node + 1]);
  const char* xlb = (const char*)xl;          // UNIFORM gather base
  const unsigned lane8 = (unsigned)lane * 8u;
  uint2 rp = ((const uint2*)xr)[(size_t)node * 64 + lane];
  float4 r = make_float4(bflo(rp.x), bfhi(rp.x), bflo(rp.y), bfhi(rp.y));
  float4 wv = ((const float4*)we)[lane];
  float4 at = ((const float4*)att)[lane];
  const float LOG2E = 1.442695040888963f;
  at.x *= LOG2E; at.y *= LOG2E; at.z *= LOG2E; at.w *= LOG2E;
  float4 acc = make_float4(0.f, 0.f, 0.f, 0.f);
  float denom = 0.f;

  auto edge_step = [&](float eav, uint2 p) {
    float4 a = make_float4(bflo(p.x), bfhi(p.x), bflo(p.y), bfhi(p.y));
    float s0 = a.x + (r.x + eav * wv.x);
    float s1 = a.y + (r.y + eav * wv.y);
    float s2 = a.z + (r.z + eav * wv.z);
    float s3 = a.w + (r.w + eav * wv.w);
    s0 = fmaxf(s0, 0.2f * s0);
    s1 = fmaxf(s1, 0.2f * s1);
    s2 = fmaxf(s2, 0.2f * s2);
    s3 = fmaxf(s3, 0.2f * s3);
    float p4 = (s0 * at.x + s1 * at.y) + (s2 * at.z + s3 * at.w);
    p4 += swz_xor(p4, 8);
    p4 += swz_xor(p4, 4);
    p4 += swz_xor(p4, 2);
    p4 += swz_xor(p4, 1);
    float ex = exp2f(p4);
    denom += ex;
    acc.x += ex * a.x; acc.y += ex * a.y; acc.z += ex * a.z; acc.w += ex * a.w;
  };
  auto gath = [&](int byteoff) {
    return *(const uint2*)(xlb + (unsigned)byteoff + lane8);
  };

  int i = r0;
  if (i + 8 <= r1) {
    int2 e0 = edges[i];     int2 e1 = edges[i + 1];
    int2 e2 = edges[i + 2]; int2 e3 = edges[i + 3];
    uint2 p0 = gath(e0.x), p1 = gath(e1.x), p2 = gath(e2.x), p3 = gath(e3.x);
    for (; i + 8 <= r1; i += 4) {
      int2 f0 = edges[i + 4]; int2 f1 = edges[i + 5];
      int2 f2 = edges[i + 6]; int2 f3 = edges[i + 7];
      uint2 q0 = gath(f0.x), q1 = gath(f1.x), q2 = gath(f2.x), q3 = gath(f3.x);
      edge_step(__int_as_float(e0.y), p0);
      edge_step(__int_as_float(e1.y), p1);
      edge_step(__int_as_float(e2.y), p2);
      edge_step(__int_as_float(e3.y), p3);
      e0 = f0; e1 = f1; e2 = f2; e3 = f3;
      p0 = q0; p1 = q1; p2 = q2; p3 = q3;
    }
    edge_step(__int_as_float(e0.y), p0);
    edge_step(__int_as_float(e1.y), p1);
    edge_step(__int_as_float(e2.y), p2);
    edge_step(__int_as_float(e3.y), p3);
    i += 4;
  } else if (i + 4 <= r1) {
    int2 e0 = edges[i];     int2 e1 = edges[i + 1];
    int2 e2 = edges[i + 2]; int2 e3 = edges[i + 3];
    uint2 p0 = gath(e0.x), p1 = gath(e1.x), p2 = gath(e2.x), p3 = gath(e3.x);
    edge_step(__int_as_float(e0.y), p0);
    edge_step(__int_as_float(e1.y), p1);
    edge_step(__int_as_float(e2.y), p2);
    edge_step(__int_as_float(e3.y), p3);
    i += 4;
  }
  for (; i < r1; ++i) {
    int2 e = edges[i];
    edge_step(__int_as_float(e.y), gath(e.x));
  }

  float inv = 1.f / (denom + 1e-16f);
  float4 bv = ((const float4*)bias)[lane];
  float4 o;
  o.x = fmaxf(acc.x * inv + bv.x, 0.f);
  o.y = fmaxf(acc.y * inv + bv.y, 0.f);
  o.z = fmaxf(acc.z * inv + bv.z, 0.f);
  o.w = fmaxf(acc.w * inv + bv.w, 0.f);
  uint2 pk;
  pk.x = (unsigned)f2bf(o.x) | ((unsigned)f2bf(o.y) << 16);
  pk.y = (unsigned)f2bf(o.z) | ((unsigned)f2bf(o.w) << 16);
  if constexpr (!POOL) {
    ((uint2*)outb)[(size_t)node * 64 + lane] = pk;
  } else {
    // bf16-rounded f32 values (bitwise = pool_kernel's summands)
    *(float4*)&pacc[wave][lane * 4] =
        make_float4(bflo(pk.x), bfhi(pk.x), bflo(pk.y), bfhi(pk.y));
    __threadfence_block();               // drain ds_writes before the bump
    int prev = 0;
    if (lane == 0) prev = atomicAdd(&done, 1);
    prev = __shfl(prev, 0, 64);
    if (prev == 3) {                     // last wave flushes; others exit now
      int b0 = pb[0], b1 = pb[1], b2 = pb[2], b3 = pb[3];
      if (b0 == b3 && b0 == b1 && b1 == b2) {   // sorted batch: common case
#pragma unroll
        for (int k = 0; k < 4; ++k) {
          int ch = lane + 64 * k;        // coalesced channel walk
          float s = (pacc[0][ch] + pacc[1][ch]) + (pacc[2][ch] + pacc[3][ch]);
          atomicAdd(&pool[b0 * 256 + ch], s);
        }
      } else {
#pragma unroll
        for (int k = 0; k < 4; ++k) {
          int ch = lane + 64 * k;
          atomicAdd(&pool[b0 * 256 + ch], pacc[0][ch]);
          atomicAdd(&pool[b1 * 256 + ch], pacc[1][ch]);
          atomicAdd(&pool[b2 * 256 + ch], pacc[2][ch]);
          atomicAdd(&pool[b3 * 256 + ch], pacc[3][ch]);
        }
      }
    }
  }
}

// ---------------- final MLP: one block (128 thr) per graph ----------------
__global__ __launch_bounds__(128) void mlp_kernel(
    const float* __restrict__ pool, const int* __restrict__ bounds,
    const float* __restrict__ p1w, const float* __restrict__ p1b,
    const float* __restrict__ lng, const float* __restrict__ lnb,
    const float* __restrict__ p2w, const float* __restrict__ p2b,
    const float* __restrict__ hw, const float* __restrict__ hb,
    float* __restrict__ out) {
  __shared__ float sg[256];
  __shared__ float red[128];
  __shared__ float sz[128];
  __shared__ float s2[64];
  int b = blockIdx.x, tid = threadIdx.x;
  float cntf = (float)(bounds[b + 1] - bounds[b]);
  float invc = 1.f / fmaxf(cntf, 1.f);
  for (int i = tid; i < 256; i += 128) sg[i] = pool[b * 256 + i] * invc;
  __syncthreads();
  float z = p1b[tid];
  for (int k = 0; k < 256; ++k) z += sg[k] * p1w[k * 128 + tid];
  red[tid] = z; __syncthreads();
  for (int off = 64; off; off >>= 1) { if (tid < off) red[tid] += red[tid + off]; __syncthreads(); }
  float mu = red[0] * (1.f / 128.f);
  __syncthreads();
  float d = z - mu;
  red[tid] = d * d; __syncthreads();
  for (int off = 64; off; off >>= 1) { if (tid < off) red[tid] += red[tid + off]; __syncthreads(); }
  float var = red[0] * (1.f / 128.f);
  float zn = d * rsqrtf(var + 1e-5f) * lng[tid] + lnb[tid];
  sz[tid] = fmaxf(zn, 0.f);
  __syncthreads();
  if (tid < 64) {
    float a = p2b[tid];
    for (int k = 0; k < 128; ++k) a += sz[k] * p2w[k * 64 + tid];
    s2[tid] = fmaxf(a, 0.f);
  }
  __syncthreads();
  if (tid < 64) {
    float p = s2[tid] * hw[tid];
    for (int off = 32; off; off >>= 1) p += __shfl_down(p, off, 64);
    if (tid == 0) out[b] = p + hb[0];
  }
}

extern "C" void kernel_launch(void* const* d_in, const int* in_sizes, int n_in,
                              void* d_out, int out_size, void* d_ws, size_t ws_size,
                              hipStream_t stream) {
  const float* x      = (const float*)d_in[0];
  const int*   ei     = (const int*)d_in[1];
  const float* ea     = (const float*)d_in[2];
  const int*   batch  = (const int*)d_in[3];
  const float* enc_w  = (const float*)d_in[4];
  const float* enc_b  = (const float*)d_in[5];
  const float* g1_wl  = (const float*)d_in[6];
  const float* g1_bl  = (const float*)d_in[7];
  const float* g1_wr  = (const float*)d_in[8];
  const float* g1_we  = (const float*)d_in[9];
  const float* g1_att = (const float*)d_in[10];
  const float* g1_b   = (const float*)d_in[11];
  const float* g2_wl  = (const float*)d_in[12];
  const float* g2_bl  = (const float*)d_in[13];
  const float* g2_wr  = (const float*)d_in[14];
  const float* g2_we  = (const float*)d_in[15];
  const float* g2_att = (const float*)d_in[16];
  const float* g2_b   = (const float*)d_in[17];
  const float* p1_w   = (const float*)d_in[18];
  const float* p1_b   = (const float*)d_in[19];
  const float* ln_g   = (const float*)d_in[20];
  const float* ln_b   = (const float*)d_in[21];
  const float* p2_w   = (const float*)d_in[22];
  const float* p2_b   = (const float*)d_in[23];
  const float* head_w = (const float*)d_in[24];
  const float* head_b = (const float*)d_in[25];
  float* out = (float*)d_out;

  char* ws = (char*)d_ws;
  size_t off = 0;
  auto alloc = [&](size_t bytes) -> void* {
    void* p = ws + off;
    off = (off + bytes + 255) & ~(size_t)255;
    return p;
  };
  unsigned short* xl   = (unsigned short*)alloc((size_t)NN * HC * 2);
  unsigned short* xr   = (unsigned short*)alloc((size_t)NN * HC * 2);
  unsigned short* h0   = (unsigned short*)alloc((size_t)NN * 64 * 2);
  unsigned short* hb16 = (unsigned short*)alloc((size_t)NN * HC * 2);
  unsigned short* wt1  = (unsigned short*)alloc((size_t)512 * 64 * 2);
  unsigned short* wt2  = (unsigned short*)alloc((size_t)512 * 256 * 2);
  float* pool      = (float*)alloc((size_t)GG * HC * 4);
  int*   deg       = (int*)alloc((size_t)NN * 4);
  int*   rowstart  = (int*)alloc((size_t)(NN + 1) * 4);
  int*   cursor    = (int*)alloc((size_t)NN * 4);
  int*   bsum      = (int*)alloc((size_t)NB * 4);
  int*   bpre      = (int*)alloc((size_t)NB * 4);
  int2*  edges     = (int2*)alloc((size_t)NE * 8);
  int*   bounds    = (int*)alloc((size_t)(GG + 1) * 4);

  // encoder + weight prep + setup (zero deg/pool, seg bounds) in ONE launch
  head_kernel<<<ENCB + WCB + NB, 256, 0, stream>>>(
      x, enc_w, enc_b, h0, g1_wl, g1_wr, g2_wl, g2_wr, wt1, wt2,
      batch, deg, pool, bounds);

  // CSR build: degree -> hierarchical scan -> fill (proven chain)
  degree_kernel<<<(NE + 255) / 256, 256, 0, stream>>>(ei, deg);
  blocksum_kernel<<<NB, 256, 0, stream>>>(deg, bsum);
  blockscan_kernel<<<1, 256, 0, stream>>>(bsum, bpre, rowstart);
  rowstart_kernel<<<NB, 256, 0, stream>>>(deg, bpre, rowstart, cursor);
  fill_kernel<<<(NE + 255) / 256, 256, 0, stream>>>(ei, ea, cursor, edges);

  const int MMB = ((NN + 127) / 128) * 4;   // 1564 matmul blocks

  // ---- GAT layer 1 (K=64): matmul -> xl/xr, then edge phase ----
  matmul_mfma_kernel<64><<<MMB, 256, 0, stream>>>(h0, wt1, g1_bl, xl, xr, NN);
  gat_fused_kernel<false><<<NN / 4, 256, 0, stream>>>(
      rowstart, edges, xl, xr, g1_we, g1_att, g1_b, hb16, batch, pool);

  // ---- GAT layer 2 (K=256): matmul, then edge phase (pool fused in) ----
  matmul_mfma_kernel<256><<<MMB, 256, 0, stream>>>(hb16, wt2, g2_bl, xl, xr, NN);
  gat_fused_kernel<true><<<NN / 4, 256, 0, stream>>>(
      rowstart, edges, xl, xr, g2_we, g2_att, g2_b, nullptr, batch, pool);

  // ---- MLP head (pool already accumulated by gat2) ----
  mlp_kernel<<<GG, 128, 0, stream>>>(pool, bounds, p1_w, p1_b, ln_g, ln_b,
                                     p2_w, p2_b, head_w, head_b, out);
}